// Round 1
// baseline (681.955 us; speedup 1.0000x reference)
//
#include <hip/hip_runtime.h>
#include <hip/hip_bf16.h>

#define B_   16
#define L_   2048
#define D1_  512
#define G_   2
#define V_   320
#define GV_  640
#define DG_  384
#define OUT0_ ((size_t)B_ * L_ * G_ * DG_)   // 25165824

// Transpose W (640x512, o-major) -> WT (512x640, k-major) for coalesced GEMM reads.
__global__ void transpose_w_kernel(const float* __restrict__ W, float* __restrict__ WT) {
    __shared__ float tile[32][33];
    int bx = blockIdx.x;  // k tile: 512/32 = 16
    int by = blockIdx.y;  // o tile: 640/32 = 20
    int tx = threadIdx.x, ty = threadIdx.y;  // 32 x 8
#pragma unroll
    for (int i = 0; i < 4; ++i)
        tile[ty + i * 8][tx] = W[(size_t)(by * 32 + ty + i * 8) * D1_ + bx * 32 + tx];
    __syncthreads();
#pragma unroll
    for (int i = 0; i < 4; ++i)
        WT[(size_t)(bx * 32 + ty + i * 8) * GV_ + by * 32 + tx] = tile[tx][ty + i * 8];
}

// One block per l. 320 threads (5 waves). Computes logits for all 16 batch rows,
// argmax (with fp64 refine for near-ties), codebook gather, and in-block perplexity.
template <bool USE_WT>
__global__ __launch_bounds__(320) void gvq_kernel(
    const float* __restrict__ hidden,   // (16, 2048, 512)
    const float* __restrict__ Wk,       // USE_WT ? WT [512][640] : W [640][512]
    const float* __restrict__ Worig,    // W [640][512] (for fp64 refine)
    const float* __restrict__ bias,     // (640)
    const float* __restrict__ codebook, // (2, 320, 384)
    const float* __restrict__ gumbel,   // (65536, 320)
    float* __restrict__ out)
{
    __shared__ union SM {
        float A[B_][D1_];    // 32 KB — input rows during GEMM
        float LG[B_][GV_];   // 40 KB — logits after GEMM (A dead by then)
    } sm;
    __shared__ float PERP[G_][V_];

    const int l = blockIdx.x;
    const int t = threadIdx.x;

    // ---- Phase 0: stage A rows, zero perplexity accumulator ----
    for (int i = t; i < B_ * D1_ / 4; i += 320) {
        int r = i >> 7, c = i & 127;  // 128 float4 per row
        ((float4*)sm.A[r])[c] = ((const float4*)(hidden + ((size_t)r * L_ + l) * D1_))[c];
    }
    for (int i = t; i < GV_; i += 320) ((float*)PERP)[i] = 0.f;
    __syncthreads();

    // ---- Phase 1: GEMM — thread owns cols o0=2t, o1=2t+1, all 16 rows ----
    float acc0[B_], acc1[B_];
#pragma unroll
    for (int r = 0; r < B_; ++r) { acc0[r] = 0.f; acc1[r] = 0.f; }
    const int o0 = 2 * t, o1 = 2 * t + 1;

    if (USE_WT) {
        for (int k4 = 0; k4 < D1_ / 4; ++k4) {
            const int k = k4 * 4;
            float2 w0 = *(const float2*)(Wk + (size_t)(k + 0) * GV_ + o0);
            float2 w1 = *(const float2*)(Wk + (size_t)(k + 1) * GV_ + o0);
            float2 w2 = *(const float2*)(Wk + (size_t)(k + 2) * GV_ + o0);
            float2 w3 = *(const float2*)(Wk + (size_t)(k + 3) * GV_ + o0);
#pragma unroll
            for (int r = 0; r < B_; ++r) {
                float4 a = ((const float4*)sm.A[r])[k4];  // wave-broadcast LDS read
                acc0[r] = fmaf(a.x, w0.x, acc0[r]); acc1[r] = fmaf(a.x, w0.y, acc1[r]);
                acc0[r] = fmaf(a.y, w1.x, acc0[r]); acc1[r] = fmaf(a.y, w1.y, acc1[r]);
                acc0[r] = fmaf(a.z, w2.x, acc0[r]); acc1[r] = fmaf(a.z, w2.y, acc1[r]);
                acc0[r] = fmaf(a.w, w3.x, acc0[r]); acc1[r] = fmaf(a.w, w3.y, acc1[r]);
            }
        }
    } else {
        for (int k4 = 0; k4 < D1_ / 4; ++k4) {
            float4 wa = ((const float4*)(Wk + (size_t)o0 * D1_))[k4];
            float4 wb = ((const float4*)(Wk + (size_t)o1 * D1_))[k4];
#pragma unroll
            for (int r = 0; r < B_; ++r) {
                float4 a = ((const float4*)sm.A[r])[k4];
                acc0[r] = fmaf(a.x, wa.x, acc0[r]); acc1[r] = fmaf(a.x, wb.x, acc1[r]);
                acc0[r] = fmaf(a.y, wa.y, acc0[r]); acc1[r] = fmaf(a.y, wb.y, acc1[r]);
                acc0[r] = fmaf(a.z, wa.z, acc0[r]); acc1[r] = fmaf(a.z, wb.z, acc1[r]);
                acc0[r] = fmaf(a.w, wa.w, acc0[r]); acc1[r] = fmaf(a.w, wb.w, acc1[r]);
            }
        }
    }
    __syncthreads();  // everyone done reading sm.A
    {
        float b0 = bias[o0], b1 = bias[o1];
#pragma unroll
        for (int r = 0; r < B_; ++r) {
            float2 v; v.x = acc0[r] + b0; v.y = acc1[r] + b1;
            *(float2*)&sm.LG[r][o0] = v;
        }
    }
    __syncthreads();

    // ---- Phase 2: per-subrow softmax/argmax. 32 subrows (b,g) over 5 waves ----
    const int wave = t >> 6;
    const int lane = t & 63;
    for (int sr = wave; sr < B_ * G_; sr += 5) {
        const int r = sr >> 1, g = sr & 1;
        const float* gptr = gumbel + (((size_t)r * L_ + l) * G_ + g) * V_;
        float lg[5], gn[5];
        float ms = -3.4e38f; int mi = 0;
        float lmax = -3.4e38f;
#pragma unroll
        for (int j = 0; j < 5; ++j) {
            const int v = lane + 64 * j;
            lg[j] = sm.LG[r][g * V_ + v];
            gn[j] = gptr[v];
            float s = lg[j] + gn[j];
            if (s > ms) { ms = s; mi = v; }   // ascending v: strict > keeps first index
            lmax = fmaxf(lmax, lg[j]);
        }
        // argmax butterfly (value desc, index asc on ties -> np.argmax semantics)
#pragma unroll
        for (int off = 1; off < 64; off <<= 1) {
            float ov = __shfl_xor(ms, off);
            int   oi = __shfl_xor(mi, off);
            if (ov > ms || (ov == ms && oi < mi)) { ms = ov; mi = oi; }
        }
        // second max (gap check)
        float m2 = -3.4e38f;
#pragma unroll
        for (int j = 0; j < 5; ++j) {
            const int v = lane + 64 * j;
            float s = lg[j] + gn[j];
            if (v != mi) m2 = fmaxf(m2, s);
        }
#pragma unroll
        for (int off = 1; off < 64; off <<= 1) m2 = fmaxf(m2, __shfl_xor(m2, off));

        int idx = mi;
        if (ms - m2 < 1e-3f) {
            // near-tie: exact fp64 re-argmax of the whole subrow (rare: ~1e-3 of rows)
            const float* arow = hidden + ((size_t)r * L_ + l) * D1_;
            double bm = -1e300; int bi = 0;
#pragma unroll
            for (int j = 0; j < 5; ++j) {
                const int v = lane + 64 * j;
                const int o = g * V_ + v;
                const float* wrow = Worig + (size_t)o * D1_;
                double s = (double)bias[o];
                for (int k = 0; k < D1_; ++k) s = fma((double)arow[k], (double)wrow[k], s);
                s += (double)gn[j];
                if (s > bm) { bm = s; bi = v; }
            }
            for (int off = 1; off < 64; off <<= 1) {
                double ov = __shfl_xor(bm, off);
                int    oi = __shfl_xor(bi, off);
                if (ov > bm || (ov == bm && oi < bi)) { bm = ov; bi = oi; }
            }
            idx = bi;
        }

        // perplexity: softmax of raw logits (no gumbel, no tau), averaged over b in-block
#pragma unroll
        for (int off = 1; off < 64; off <<= 1) lmax = fmaxf(lmax, __shfl_xor(lmax, off));
        float e[5], lsum = 0.f;
#pragma unroll
        for (int j = 0; j < 5; ++j) { e[j] = expf(lg[j] - lmax); lsum += e[j]; }
#pragma unroll
        for (int off = 1; off < 64; off <<= 1) lsum += __shfl_xor(lsum, off);
        float scale = 1.0f / (lsum * (float)B_);
#pragma unroll
        for (int j = 0; j < 5; ++j) atomicAdd(&PERP[g][lane + 64 * j], e[j] * scale);

        // code vector: straight gather of codebook row idx
        const float* cb = codebook + ((size_t)g * V_ + idx) * DG_;
        float* op = out + ((size_t)r * L_ + l) * (G_ * DG_) + (size_t)g * DG_;
#pragma unroll
        for (int j = 0; j < DG_ / 64; ++j) op[lane + 64 * j] = cb[lane + 64 * j];
    }

    __syncthreads();
    // ---- Phase 3: write perplexity (l, g, v) ----
    for (int i = t; i < GV_; i += 320)
        out[OUT0_ + (size_t)l * GV_ + i] = ((const float*)PERP)[i];
}

extern "C" void kernel_launch(void* const* d_in, const int* in_sizes, int n_in,
                              void* d_out, int out_size, void* d_ws, size_t ws_size,
                              hipStream_t stream) {
    const float* hidden   = (const float*)d_in[0];
    const float* W        = (const float*)d_in[1];
    const float* bias     = (const float*)d_in[2];
    const float* codebook = (const float*)d_in[3];
    const float* gumbel   = (const float*)d_in[4];
    float* out = (float*)d_out;

    const size_t wt_bytes = (size_t)GV_ * D1_ * sizeof(float);
    if (ws_size >= wt_bytes) {
        float* WT = (float*)d_ws;
        transpose_w_kernel<<<dim3(16, 20), dim3(32, 8), 0, stream>>>(W, WT);
        gvq_kernel<true><<<dim3(L_), dim3(320), 0, stream>>>(hidden, WT, W, bias, codebook, gumbel, out);
    } else {
        gvq_kernel<false><<<dim3(L_), dim3(320), 0, stream>>>(hidden, W, W, bias, codebook, gumbel, out);
    }
}

// Round 2
// 344.654 us; speedup vs baseline: 1.9787x; 1.9787x over previous
//
#include <hip/hip_runtime.h>

#define B_    16
#define L_    2048
#define D1_   512
#define G_    2
#define V_    320
#define GV_   640
#define DG_   384
#define NB_   256
#define NT_   512
#define LPB_  8
#define ROWS_ 128
#define OUT0_ ((size_t)B_ * L_ * G_ * DG_)
#define WS_PLANE_ ((size_t)GV_ * D1_)            // ushorts per plane
#define WS_BYTES_ (2u * GV_ * D1_ * 2u)          // 1,310,720
#define THR_ 3e-4f

typedef __attribute__((ext_vector_type(8))) short s16x8;
typedef __attribute__((ext_vector_type(4))) float f32x4;
typedef __attribute__((ext_vector_type(4))) int   s32x4;
typedef __attribute__((ext_vector_type(4))) unsigned short u16x4;

__device__ __forceinline__ unsigned short f2bf(float x) {
    unsigned u = __float_as_uint(x);
    u += 0x7fffu + ((u >> 16) & 1u);
    return (unsigned short)(u >> 16);
}
__device__ __forceinline__ float bf2f(unsigned short h) {
    return __uint_as_float(((unsigned)h) << 16);
}
// top-2 (val desc, idx asc on tie) merge: (m1,i1,m2,i2) <- merge with (om1,oi1,om2,oi2)
__device__ __forceinline__ void merge2(float& m1, int& i1, float& m2, int& i2,
                                       float om1, int oi1, float om2, int oi2) {
    if (om1 > m1 || (om1 == m1 && oi1 < i1)) {
        if (m1 > om2 || (m1 == om2 && i1 < oi2)) { m2 = m1; i2 = i1; }
        else                                     { m2 = om2; i2 = oi2; }
        m1 = om1; i1 = oi1;
    } else if (om1 > m2 || (om1 == m2 && oi1 < i2)) { m2 = om1; i2 = oi1; }
}

// W (640x512 fp32) -> ws: bf16 hi plane + lo plane, MFMA-frag layout
// element (o,k): chunk n=o>>4, kk=k>>5, lane=(o&15)+16*((k>>3)&3), j=k&7
__global__ void prep_w_kernel(const float* __restrict__ W, unsigned short* __restrict__ ws) {
    int flat = blockIdx.x * 256 + threadIdx.x;   // 0..81919
    int o  = flat >> 7;
    int j0 = (flat & 127) << 2;
    float4 v = *(const float4*)(W + (size_t)o * D1_ + j0);
    float vv[4] = {v.x, v.y, v.z, v.w};
    u16x4 hi, lo;
#pragma unroll
    for (int i = 0; i < 4; ++i) {
        unsigned short h = f2bf(vv[i]);
        hi[i] = h;
        lo[i] = f2bf(vv[i] - bf2f(h));
    }
    int n  = o >> 4;
    int kk = j0 >> 5;
    int ls = (o & 15) + (((j0 >> 3) & 3) << 4);
    size_t off = (((size_t)(n * 16 + kk) * 64 + ls) << 3) + (j0 & 7);
    *(u16x4*)(ws + off)             = hi;
    *(u16x4*)(ws + WS_PLANE_ + off) = lo;
}

__global__ __launch_bounds__(NT_, 2) void gvq_mfma_kernel(
    const float* __restrict__ hidden,
    const float* __restrict__ W,
    const float* __restrict__ bias,
    const float* __restrict__ cb,
    const float* __restrict__ gn,
    float* __restrict__ out,
    const unsigned short* __restrict__ wsW,
    int has_ws)
{
    __shared__ union {
        struct {                              // GEMM phase: 57344 B
            unsigned short Ahi[8 * 64 * 8];
            unsigned short Alo[8 * 64 * 8];
            unsigned short Wb [40 * 64 * 8];
        } g;
        struct {                              // epilogue: 54272 B
            float pm1[4][128]; int pi1[4][128];
            float pm2[4][128]; int pi2[4][128];
            float plx[4][128]; float psum[4][128];
            int   IDX[128][2];
            float PERP[2][8][640];
        } e;
    } sm;

    const int tid  = threadIdx.x;
    const int w    = tid >> 6;
    const int lane = tid & 63;
    const int rg   = w >> 2;       // row-group (64 rows)
    const int cg   = w & 3;        // col-group (160 cols)
    const int q    = lane >> 4;
    const int c    = lane & 15;
    const int bid  = blockIdx.x;
    const int gown = cg >> 1;      // this wave's g

    // ---- A staging constants (2 float4 per thread per ktile) ----
    const int aj0 = (tid & 7) << 2;          // 0..28
    const int ar0 = tid >> 3;                // row 0..63 (it=0), +64 (it=1)
    const int ar1 = ar0 + 64;
    const size_t abase0 = ((size_t)(ar0 >> 3) * L_ + (size_t)(bid * LPB_ + (ar0 & 7))) * D1_ + aj0;
    const size_t abase1 = ((size_t)(ar1 >> 3) * L_ + (size_t)(bid * LPB_ + (ar1 & 7))) * D1_ + aj0;
    const int aoff0 = (((ar0 >> 4) * 64 + (ar0 & 15) + (((aj0 >> 3) & 3) << 4)) << 3) + (aj0 & 7);
    const int aoff1 = (((ar1 >> 4) * 64 + (ar1 & 15) + (((aj0 >> 3) & 3) << 4)) << 3) + (aj0 & 7);

    f32x4 acc[4][10];
#pragma unroll
    for (int rf = 0; rf < 4; ++rf)
#pragma unroll
        for (int cf = 0; cf < 10; ++cf)
            acc[rf][cf] = (f32x4){0.f, 0.f, 0.f, 0.f};

#pragma unroll 1
    for (int kk = 0; kk < 16; ++kk) {
        // ---- stage A (hi+lo) ----
        {
            float4 v0 = *(const float4*)(hidden + abase0 + kk * 32);
            float4 v1 = *(const float4*)(hidden + abase1 + kk * 32);
            float a0[4] = {v0.x, v0.y, v0.z, v0.w};
            float a1[4] = {v1.x, v1.y, v1.z, v1.w};
            u16x4 h0, l0, h1, l1;
#pragma unroll
            for (int i = 0; i < 4; ++i) {
                unsigned short h = f2bf(a0[i]); h0[i] = h; l0[i] = f2bf(a0[i] - bf2f(h));
                h = f2bf(a1[i]); h1[i] = h; l1[i] = f2bf(a1[i] - bf2f(h));
            }
            *(u16x4*)(sm.g.Ahi + aoff0) = h0; *(u16x4*)(sm.g.Alo + aoff0) = l0;
            *(u16x4*)(sm.g.Ahi + aoff1) = h1; *(u16x4*)(sm.g.Alo + aoff1) = l1;
        }
        // ---- stage W hi plane ----
        if (has_ws) {
#pragma unroll
            for (int it = 0; it < 5; ++it) {
                int ch = w + it * 8;         // 0..39
                const float4* src = (const float4*)(wsW + (((size_t)(ch * 16 + kk) * 64 + lane) << 3));
                *(float4*)(sm.g.Wb + (((size_t)ch * 64 + lane) << 3)) = *src;
            }
        } else {
#pragma unroll
            for (int it = 0; it < 10; ++it) {
                int i = tid + it * NT_;      // 0..5119
                int o = i >> 3, j0 = (i & 7) << 2;
                float4 v = *(const float4*)(W + (size_t)o * D1_ + kk * 32 + j0);
                float vv[4] = {v.x, v.y, v.z, v.w};
                u16x4 hh;
#pragma unroll
                for (int x = 0; x < 4; ++x) hh[x] = f2bf(vv[x]);
                int off = (((o >> 4) * 64 + (o & 15) + (((j0 >> 3) & 3) << 4)) << 3) + (j0 & 7);
                *(u16x4*)(sm.g.Wb + off) = hh;
            }
        }
        __syncthreads();

        s16x8 ah[4], al[4];
#pragma unroll
        for (int rf = 0; rf < 4; ++rf) {
            ah[rf] = *(const s16x8*)(sm.g.Ahi + ((((rg << 2) + rf) * 64 + lane) << 3));
            al[rf] = *(const s16x8*)(sm.g.Alo + ((((rg << 2) + rf) * 64 + lane) << 3));
        }
#pragma unroll
        for (int cf = 0; cf < 10; ++cf) {
            s16x8 bh = *(const s16x8*)(sm.g.Wb + (((cg * 10 + cf) * 64 + lane) << 3));
#pragma unroll
            for (int rf = 0; rf < 4; ++rf) {
                acc[rf][cf] = __builtin_amdgcn_mfma_f32_16x16x32_bf16(ah[rf], bh, acc[rf][cf], 0, 0, 0);
                acc[rf][cf] = __builtin_amdgcn_mfma_f32_16x16x32_bf16(al[rf], bh, acc[rf][cf], 0, 0, 0);
            }
        }
        __syncthreads();
        // ---- stage W lo plane ----
        if (has_ws) {
#pragma unroll
            for (int it = 0; it < 5; ++it) {
                int ch = w + it * 8;
                const float4* src = (const float4*)(wsW + WS_PLANE_ + (((size_t)(ch * 16 + kk) * 64 + lane) << 3));
                *(float4*)(sm.g.Wb + (((size_t)ch * 64 + lane) << 3)) = *src;
            }
        } else {
#pragma unroll
            for (int it = 0; it < 10; ++it) {
                int i = tid + it * NT_;
                int o = i >> 3, j0 = (i & 7) << 2;
                float4 v = *(const float4*)(W + (size_t)o * D1_ + kk * 32 + j0);
                float vv[4] = {v.x, v.y, v.z, v.w};
                u16x4 ll;
#pragma unroll
                for (int x = 0; x < 4; ++x) { unsigned short h = f2bf(vv[x]); ll[x] = f2bf(vv[x] - bf2f(h)); }
                int off = (((o >> 4) * 64 + (o & 15) + (((j0 >> 3) & 3) << 4)) << 3) + (j0 & 7);
                *(u16x4*)(sm.g.Wb + off) = ll;
            }
        }
        __syncthreads();
#pragma unroll
        for (int cf = 0; cf < 10; ++cf) {
            s16x8 bl = *(const s16x8*)(sm.g.Wb + (((cg * 10 + cf) * 64 + lane) << 3));
#pragma unroll
            for (int rf = 0; rf < 4; ++rf)
                acc[rf][cf] = __builtin_amdgcn_mfma_f32_16x16x32_bf16(ah[rf], bl, acc[rf][cf], 0, 0, 0);
        }
        __syncthreads();
    }

    // ---- E1: bias ----
    float bv[10];
#pragma unroll
    for (int cf = 0; cf < 10; ++cf) bv[cf] = bias[cg * 160 + cf * 16 + c];
#pragma unroll
    for (int rf = 0; rf < 4; ++rf)
#pragma unroll
        for (int cf = 0; cf < 10; ++cf)
#pragma unroll
            for (int r = 0; r < 4; ++r) acc[rf][cf][r] += bv[cf];

    // ---- E2: per-(row,g-partial) top2(s=logit+gumbel) and max(logit), per col-group ----
#pragma unroll
    for (int rf = 0; rf < 4; ++rf) {
        size_t gb[4];
#pragma unroll
        for (int r = 0; r < 4; ++r) {
            int row = rg * 64 + rf * 16 + q * 4 + r;
            int b = row >> 3, ll = bid * LPB_ + (row & 7);
            gb[r] = (((size_t)b * L_ + ll) * G_ + gown) * V_ + (cg & 1) * 160 + c;
        }
        float m1[4], m2[4], lx[4]; int i1[4], i2[4];
#pragma unroll
        for (int r = 0; r < 4; ++r) { m1[r] = -3.0e38f; m2[r] = -3.0e38f; lx[r] = -3.0e38f; i1[r] = 0; i2[r] = 0; }
#pragma unroll
        for (int cf = 0; cf < 10; ++cf) {
            int col = cg * 160 + cf * 16 + c;
#pragma unroll
            for (int r = 0; r < 4; ++r) {
                float lg = acc[rf][cf][r];
                float s  = lg + gn[gb[r] + cf * 16];
                lx[r] = fmaxf(lx[r], lg);
                if (s > m1[r])      { m2[r] = m1[r]; i2[r] = i1[r]; m1[r] = s; i1[r] = col; }
                else if (s > m2[r]) { m2[r] = s; i2[r] = col; }
            }
        }
#pragma unroll
        for (int mk = 1; mk <= 8; mk <<= 1) {
#pragma unroll
            for (int r = 0; r < 4; ++r) {
                float om1 = __shfl_xor(m1[r], mk); int oi1 = __shfl_xor(i1[r], mk);
                float om2 = __shfl_xor(m2[r], mk); int oi2 = __shfl_xor(i2[r], mk);
                float olx = __shfl_xor(lx[r], mk);
                lx[r] = fmaxf(lx[r], olx);
                merge2(m1[r], i1[r], m2[r], i2[r], om1, oi1, om2, oi2);
            }
        }
        if (c == 0) {
            int row0 = rg * 64 + rf * 16 + q * 4;
            *(f32x4*)&sm.e.pm1[cg][row0] = (f32x4){m1[0], m1[1], m1[2], m1[3]};
            *(s32x4*)&sm.e.pi1[cg][row0] = (s32x4){i1[0], i1[1], i1[2], i1[3]};
            *(f32x4*)&sm.e.pm2[cg][row0] = (f32x4){m2[0], m2[1], m2[2], m2[3]};
            *(s32x4*)&sm.e.pi2[cg][row0] = (s32x4){i2[0], i2[1], i2[2], i2[3]};
            *(f32x4*)&sm.e.plx[cg][row0] = (f32x4){lx[0], lx[1], lx[2], lx[3]};
        }
    }
    __syncthreads();

    // ---- E3: global row-max (per g), exp, sumexp ----
    float LM[4][4], IZ[4][4];
    const int cA = 2 * gown, cB = cA + 1;
#pragma unroll
    for (int rf = 0; rf < 4; ++rf) {
        int row0 = rg * 64 + rf * 16 + q * 4;
        f32x4 lxA = *(const f32x4*)&sm.e.plx[cA][row0];
        f32x4 lxB = *(const f32x4*)&sm.e.plx[cB][row0];
        float se[4] = {0.f, 0.f, 0.f, 0.f};
#pragma unroll
        for (int r = 0; r < 4; ++r) LM[rf][r] = fmaxf(lxA[r], lxB[r]);
#pragma unroll
        for (int cf = 0; cf < 10; ++cf)
#pragma unroll
            for (int r = 0; r < 4; ++r) {
                float e = __expf(acc[rf][cf][r] - LM[rf][r]);
                acc[rf][cf][r] = e;
                se[r] += e;
            }
#pragma unroll
        for (int mk = 1; mk <= 8; mk <<= 1)
#pragma unroll
            for (int r = 0; r < 4; ++r) se[r] += __shfl_xor(se[r], mk);
        if (c == 0) *(f32x4*)&sm.e.psum[cg][row0] = (f32x4){se[0], se[1], se[2], se[3]};
    }
    __syncthreads();
#pragma unroll
    for (int rf = 0; rf < 4; ++rf) {
        int row0 = rg * 64 + rf * 16 + q * 4;
        f32x4 sA = *(const f32x4*)&sm.e.psum[cA][row0];
        f32x4 sB = *(const f32x4*)&sm.e.psum[cB][row0];
#pragma unroll
        for (int r = 0; r < 4; ++r) IZ[rf][r] = 1.0f / ((sA[r] + sB[r]) * 16.0f);
    }

    // ---- E4: perplexity partial over b, into LDS ----
#pragma unroll
    for (int cf = 0; cf < 10; ++cf) {
        float pp[4];
#pragma unroll
        for (int r = 0; r < 4; ++r)
            pp[r] = acc[0][cf][r] * IZ[0][r] + acc[1][cf][r] * IZ[1][r]
                  + acc[2][cf][r] * IZ[2][r] + acc[3][cf][r] * IZ[3][r];
#pragma unroll
        for (int r = 0; r < 4; ++r) pp[r] += __shfl_xor(pp[r], 32);
        if (q < 2) {
            int col = cg * 160 + cf * 16 + c;
#pragma unroll
            for (int r = 0; r < 4; ++r) sm.e.PERP[rg][q * 4 + r][col] = pp[r];
        }
    }
    __syncthreads();

    // ---- E5: perplexity out ----
#pragma unroll
    for (int it = 0; it < 10; ++it) {
        int i = tid + it * NT_;          // 0..5119
        int ll = i / GV_, colx = i - ll * GV_;
        out[OUT0_ + (size_t)(bid * LPB_ + ll) * GV_ + colx] = sm.e.PERP[0][ll][colx] + sm.e.PERP[1][ll][colx];
    }

    // ---- E6: argmax finalize (+rare fp64 refine), one row-g per lane on rg==0 waves ----
    if (rg == 0) {
        int row = (((q << 1) + (cg & 1)) << 4) + c;   // 0..127
        float M1 = sm.e.pm1[cA][row]; int I1 = sm.e.pi1[cA][row];
        float M2 = sm.e.pm2[cA][row]; int I2 = sm.e.pi2[cA][row];
        merge2(M1, I1, M2, I2, sm.e.pm1[cB][row], sm.e.pi1[cB][row],
                               sm.e.pm2[cB][row], sm.e.pi2[cB][row]);
        int idx = I1;
        if (M1 - M2 < THR_) {
            int b = row >> 3, ll = bid * LPB_ + (row & 7);
            const float* ar = hidden + ((size_t)b * L_ + ll) * D1_;
            double s1 = (double)bias[I1], s2 = (double)bias[I2];
            const float* w1 = W + (size_t)I1 * D1_;
            const float* w2 = W + (size_t)I2 * D1_;
#pragma unroll 4
            for (int k = 0; k < D1_; ++k) {
                double a = (double)ar[k];
                s1 = fma(a, (double)w1[k], s1);
                s2 = fma(a, (double)w2[k], s2);
            }
            size_t gbase = (((size_t)b * L_ + ll) * G_ + gown) * V_;
            s1 += (double)gn[gbase + (I1 - gown * V_)];
            s2 += (double)gn[gbase + (I2 - gown * V_)];
            if (s2 > s1 || (s2 == s1 && I2 < I1)) idx = I2;
        }
        sm.e.IDX[row][gown] = idx - gown * V_;
    }
    __syncthreads();

    // ---- E7: code-vector gather ----
#pragma unroll 1
    for (int it = 0; it < 48; ++it) {
        int i = tid + it * NT_;            // 0..24575
        int task = i / 96, f = i - task * 96;
        int row = task >> 1, gg = task & 1;
        int v = sm.e.IDX[row][gg];
        int b = row >> 3, ll = bid * LPB_ + (row & 7);
        float4 val = *(const float4*)(cb + ((size_t)(gg * V_ + v) * DG_) + f * 4);
        *(float4*)(out + ((size_t)b * L_ + ll) * (G_ * DG_) + gg * DG_ + f * 4) = val;
    }
}

extern "C" void kernel_launch(void* const* d_in, const int* in_sizes, int n_in,
                              void* d_out, int out_size, void* d_ws, size_t ws_size,
                              hipStream_t stream) {
    const float* hidden   = (const float*)d_in[0];
    const float* W        = (const float*)d_in[1];
    const float* bias     = (const float*)d_in[2];
    const float* codebook = (const float*)d_in[3];
    const float* gumbel   = (const float*)d_in[4];
    float* out = (float*)d_out;

    int has_ws = (ws_size >= (size_t)WS_BYTES_) ? 1 : 0;
    if (has_ws) {
        prep_w_kernel<<<320, 256, 0, stream>>>(W, (unsigned short*)d_ws);
    }
    gvq_mfma_kernel<<<NB_, NT_, 0, stream>>>(hidden, W, bias, codebook, gumbel, out,
                                             (const unsigned short*)d_ws, has_ws);
}

// Round 3
// 239.292 us; speedup vs baseline: 2.8499x; 1.4403x over previous
//
#include <hip/hip_runtime.h>

#define B_    16
#define L_    2048
#define D1_   512
#define G_    2
#define V_    320
#define GV_   640
#define DG_   384
#define OUT0_ ((size_t)B_ * L_ * G_ * DG_)
#define WS_BYTES_ ((size_t)GV_ * D1_ * 2u)   // 655360: bf16-hi plane of W in frag layout
#define THR_ 4e-3f

typedef __attribute__((ext_vector_type(8))) short          s16x8;
typedef __attribute__((ext_vector_type(8))) unsigned short u16x8;
typedef __attribute__((ext_vector_type(4))) float          f32x4;
typedef __attribute__((ext_vector_type(4))) int            s32x4;

__device__ __forceinline__ unsigned short f2bf(float x) {
    unsigned u = __float_as_uint(x);
    u += 0x7fffu + ((u >> 16) & 1u);
    return (unsigned short)(u >> 16);
}
__device__ __forceinline__ float bf2f(unsigned short h) {
    return __uint_as_float(((unsigned)h) << 16);
}
__device__ __forceinline__ void merge2(float& m1, int& i1, float& m2, int& i2,
                                       float om1, int oi1, float om2, int oi2) {
    if (om1 > m1 || (om1 == m1 && oi1 < i1)) {
        if (m1 > om2 || (m1 == om2 && i1 < oi2)) { m2 = m1; i2 = i1; }
        else                                     { m2 = om2; i2 = oi2; }
        m1 = om1; i1 = oi1;
    } else if (om1 > m2 || (om1 == m2 && oi1 < i2)) { m2 = om1; i2 = oi1; }
}
__device__ __forceinline__ void cvt8(const float4& v0, const float4& v1, u16x8& hi, u16x8& lo) {
    float a[8] = {v0.x, v0.y, v0.z, v0.w, v1.x, v1.y, v1.z, v1.w};
#pragma unroll
    for (int i = 0; i < 8; ++i) {
        unsigned short h = f2bf(a[i]);
        hi[i] = h;
        lo[i] = f2bf(a[i] - bf2f(h));
    }
}

// W (640x512 fp32) -> ws: bf16 HI plane only, MFMA B-frag layout.
// element (o,k): ch=o>>4, kk=k>>5, slot=(o&15)+16*((k>>3)&3), j=k&7
// ushort off = ((ch*16+kk)*64 + slot)*8 + j
__global__ void prep_w_kernel(const float* __restrict__ W, unsigned short* __restrict__ ws) {
    int flat = blockIdx.x * 256 + threadIdx.x;   // 81920 threads, float4 each
    int o  = flat >> 7;
    int j0 = (flat & 127) << 2;
    float4 v = *(const float4*)(W + (size_t)o * D1_ + j0);
    float vv[4] = {v.x, v.y, v.z, v.w};
    unsigned short h0 = f2bf(vv[0]), h1 = f2bf(vv[1]), h2 = f2bf(vv[2]), h3 = f2bf(vv[3]);
    int ch = o >> 4, kk = j0 >> 5;
    int slot = (o & 15) + (((j0 >> 3) & 3) << 4);
    size_t off = (((size_t)(ch * 16 + kk) * 64 + slot) << 3) + (j0 & 7);
    ws[off + 0] = h0; ws[off + 1] = h1; ws[off + 2] = h2; ws[off + 3] = h3;
}

// 512 blocks = 256 l-chunks x 2 groups. Block: 128 rows (16b x 8l, row=l_in*16+b) x 320 cols.
// 8 waves = 4 rg x 2 cg; wave tile: 32 rows (2 rf) x 160 cols (10 cf). acc 80 f32/lane.
template<bool HAS_WS>
__global__ __launch_bounds__(512, 4) void gvq3_kernel(
    const float* __restrict__ hidden,
    const float* __restrict__ W,
    const float* __restrict__ bias,
    const float* __restrict__ cb,
    const float* __restrict__ gn,
    float* __restrict__ out,
    const unsigned short* __restrict__ ws)
{
    __shared__ unsigned short Abuf[2][2][4096];          // [dbuf][hi/lo][8 chunks x 512B]
    __shared__ unsigned short Wb[HAS_WS ? 64 : 10240];   // fallback W-hi frag staging
    __shared__ float pm1[2][128], pm2[2][128], plx[2][128], psum[2][128];
    __shared__ int   pi1[2][128], pi2[2][128], IDX[128];

    const int tid  = threadIdx.x;
    const int w    = tid >> 6, lane = tid & 63;
    const int rg   = w >> 1, cg = w & 1;
    const int q    = lane >> 4, c = lane & 15;

    // XCD swizzle: both g of an l-chunk land on the same XCD (d%8 equal)
    const int d  = blockIdx.x;
    const int g  = (d >> 3) & 1;
    const int lchunk = (d >> 4) * 8 + (d & 7);
    const size_t lbase = (size_t)lchunk * 8;

    // ---- A staging map: thread -> (row r_, k-quarter kq); one 16B frag per plane ----
    const int r_ = tid >> 2, kq = tid & 3;
    const float* aptr = hidden + ((size_t)(r_ & 15) * L_ + (lbase + (r_ >> 4))) * D1_ + kq * 8;
    const int awoff = (r_ >> 4) * 1024 + (((((r_ & 15) + kq * 16) << 4)) ^ (kq << 4));
    const int rdoff = (lane << 4) ^ (lane & 48);         // swizzled frag-read byte offset

    f32x4 acc[2][10];
#pragma unroll
    for (int rf = 0; rf < 2; ++rf)
#pragma unroll
        for (int cf = 0; cf < 10; ++cf) acc[rf][cf] = (f32x4){0.f, 0.f, 0.f, 0.f};

    const unsigned short* wsb = ws + ((size_t)(g * 20 + cg * 10) << 13) + (lane << 3);

    // ---- prologue: stage A(0) (+W(0) fallback) ----
    {
        float4 v0 = *(const float4*)(aptr);
        float4 v1 = *(const float4*)(aptr + 4);
        u16x8 hi, lo; cvt8(v0, v1, hi, lo);
        *(u16x8*)((char*)Abuf[0][0] + awoff) = hi;
        *(u16x8*)((char*)Abuf[0][1] + awoff) = lo;
        if (!HAS_WS) {
#pragma unroll
            for (int i = 0; i < 3; ++i) {
                int ti = tid + i * 512;
                if (ti < 1280) {
                    int oc = ti >> 2, kq2 = ti & 3;
                    const float* wp = W + ((size_t)(g * V_ + oc)) * D1_ + kq2 * 8;
                    float4 w0 = *(const float4*)(wp), w1 = *(const float4*)(wp + 4);
                    u16x8 h, l; cvt8(w0, w1, h, l);
                    int off = (oc >> 4) * 1024 + (((((oc & 15) + kq2 * 16) << 4)) ^ (kq2 << 4));
                    *(u16x8*)((char*)Wb + off) = h;
                }
            }
        }
    }

    int cur = 0;
#pragma unroll 1
    for (int kk = 0; kk < 16; ++kk) {
        float4 av0, av1, w00[3], w01[3];
        if (kk < 15) {
            av0 = *(const float4*)(aptr + (kk + 1) * 32);
            av1 = *(const float4*)(aptr + (kk + 1) * 32 + 4);
            if (!HAS_WS) {
#pragma unroll
                for (int i = 0; i < 3; ++i) {
                    int ti = tid + i * 512;
                    if (ti < 1280) {
                        int oc = ti >> 2, kq2 = ti & 3;
                        const float* wp = W + ((size_t)(g * V_ + oc)) * D1_ + (kk + 1) * 32 + kq2 * 8;
                        w00[i] = *(const float4*)(wp); w01[i] = *(const float4*)(wp + 4);
                    }
                }
            }
        }
        __syncthreads();

        s16x8 ah[2], al[2];
#pragma unroll
        for (int rf = 0; rf < 2; ++rf) {
            const char* ab = (const char*)Abuf[cur][0] + (rg * 2 + rf) * 1024 + rdoff;
            const char* lb = (const char*)Abuf[cur][1] + (rg * 2 + rf) * 1024 + rdoff;
            ah[rf] = *(const s16x8*)ab;
            al[rf] = *(const s16x8*)lb;
        }
#pragma unroll
        for (int cf = 0; cf < 10; ++cf) {
            s16x8 bh;
            if (HAS_WS) bh = *(const s16x8*)(wsb + cf * 8192 + kk * 512);
            else        bh = *(const s16x8*)((const char*)Wb + (cg * 10 + cf) * 1024 + rdoff);
            acc[0][cf] = __builtin_amdgcn_mfma_f32_16x16x32_bf16(ah[0], bh, acc[0][cf], 0, 0, 0);
            acc[0][cf] = __builtin_amdgcn_mfma_f32_16x16x32_bf16(al[0], bh, acc[0][cf], 0, 0, 0);
            acc[1][cf] = __builtin_amdgcn_mfma_f32_16x16x32_bf16(ah[1], bh, acc[1][cf], 0, 0, 0);
            acc[1][cf] = __builtin_amdgcn_mfma_f32_16x16x32_bf16(al[1], bh, acc[1][cf], 0, 0, 0);
        }
        if (!HAS_WS) __syncthreads();
        if (kk < 15) {
            u16x8 hi, lo; cvt8(av0, av1, hi, lo);
            *(u16x8*)((char*)Abuf[cur ^ 1][0] + awoff) = hi;
            *(u16x8*)((char*)Abuf[cur ^ 1][1] + awoff) = lo;
            if (!HAS_WS) {
#pragma unroll
                for (int i = 0; i < 3; ++i) {
                    int ti = tid + i * 512;
                    if (ti < 1280) {
                        int oc = ti >> 2, kq2 = ti & 3;
                        u16x8 h, l; cvt8(w00[i], w01[i], h, l);
                        int off = (oc >> 4) * 1024 + (((((oc & 15) + kq2 * 16) << 4)) ^ (kq2 << 4));
                        *(u16x8*)((char*)Wb + off) = h;
                    }
                }
            }
            cur ^= 1;
        }
    }

    // ---- E1: bias ----
    const int lcol0 = cg * 160 + c;
    float bv[10];
#pragma unroll
    for (int cf = 0; cf < 10; ++cf) bv[cf] = bias[g * V_ + lcol0 + cf * 16];
#pragma unroll
    for (int rf = 0; rf < 2; ++rf)
#pragma unroll
        for (int cf = 0; cf < 10; ++cf)
#pragma unroll
            for (int r = 0; r < 4; ++r) acc[rf][cf][r] += bv[cf];

    // ---- E2: per-row top2(logit+gumbel) + max(logit), per cg ----
#pragma unroll
    for (int rf = 0; rf < 2; ++rf) {
        const size_t lg2 = lbase + rg * 2 + rf;
        size_t gbase[4];
#pragma unroll
        for (int r = 0; r < 4; ++r)
            gbase[r] = (((size_t)(q * 4 + r) * L_ + lg2) * G_ + g) * V_ + lcol0;
        float m1[4], m2[4], lx[4]; int i1[4], i2[4];
#pragma unroll
        for (int r = 0; r < 4; ++r) { m1[r] = -3e38f; m2[r] = -3e38f; lx[r] = -3e38f; i1[r] = 0; i2[r] = 0; }
#pragma unroll
        for (int cf = 0; cf < 10; ++cf) {
            const int col = lcol0 + cf * 16;
#pragma unroll
            for (int r = 0; r < 4; ++r) {
                float lg = acc[rf][cf][r];
                float s  = lg + gn[gbase[r] + cf * 16];
                lx[r] = fmaxf(lx[r], lg);
                if (s > m1[r])      { m2[r] = m1[r]; i2[r] = i1[r]; m1[r] = s; i1[r] = col; }
                else if (s > m2[r]) { m2[r] = s; i2[r] = col; }
            }
        }
#pragma unroll
        for (int mk = 1; mk <= 8; mk <<= 1) {
#pragma unroll
            for (int r = 0; r < 4; ++r) {
                float om1 = __shfl_xor(m1[r], mk); int oi1 = __shfl_xor(i1[r], mk);
                float om2 = __shfl_xor(m2[r], mk); int oi2 = __shfl_xor(i2[r], mk);
                lx[r] = fmaxf(lx[r], __shfl_xor(lx[r], mk));
                merge2(m1[r], i1[r], m2[r], i2[r], om1, oi1, om2, oi2);
            }
        }
        if (c == 0) {
            int row0 = (rg * 2 + rf) * 16 + q * 4;
            *(f32x4*)&pm1[cg][row0] = (f32x4){m1[0], m1[1], m1[2], m1[3]};
            *(s32x4*)&pi1[cg][row0] = (s32x4){i1[0], i1[1], i1[2], i1[3]};
            *(f32x4*)&pm2[cg][row0] = (f32x4){m2[0], m2[1], m2[2], m2[3]};
            *(s32x4*)&pi2[cg][row0] = (s32x4){i2[0], i2[1], i2[2], i2[3]};
            *(f32x4*)&plx[cg][row0] = (f32x4){lx[0], lx[1], lx[2], lx[3]};
        }
    }
    __syncthreads();

    // ---- E3a: row max -> exp -> row sum ----
#pragma unroll
    for (int rf = 0; rf < 2; ++rf) {
        int row0 = (rg * 2 + rf) * 16 + q * 4;
        float LM[4], se[4];
#pragma unroll
        for (int r = 0; r < 4; ++r) { LM[r] = fmaxf(plx[0][row0 + r], plx[1][row0 + r]); se[r] = 0.f; }
#pragma unroll
        for (int cf = 0; cf < 10; ++cf)
#pragma unroll
            for (int r = 0; r < 4; ++r) {
                float e = __expf(acc[rf][cf][r] - LM[r]);
                acc[rf][cf][r] = e; se[r] += e;
            }
#pragma unroll
        for (int mk = 1; mk <= 8; mk <<= 1)
#pragma unroll
            for (int r = 0; r < 4; ++r) se[r] += __shfl_xor(se[r], mk);
        if (c == 0) *(f32x4*)&psum[cg][row0] = (f32x4){se[0], se[1], se[2], se[3]};
    }
    __syncthreads();

    // ---- E3b + E4: scale, b-sum, direct perp store ----
#pragma unroll
    for (int rf = 0; rf < 2; ++rf) {
        int row0 = (rg * 2 + rf) * 16 + q * 4;
        float IZ[4];
#pragma unroll
        for (int r = 0; r < 4; ++r) IZ[r] = 1.0f / ((psum[0][row0 + r] + psum[1][row0 + r]) * 16.0f);
        size_t obase = OUT0_ + (lbase + rg * 2 + rf) * GV_ + g * V_ + lcol0;
#pragma unroll
        for (int cf = 0; cf < 10; ++cf) {
            float pp = acc[rf][cf][0] * IZ[0] + acc[rf][cf][1] * IZ[1]
                     + acc[rf][cf][2] * IZ[2] + acc[rf][cf][3] * IZ[3];
            pp += __shfl_xor(pp, 16); pp += __shfl_xor(pp, 32);
            if (q == 0) out[obase + cf * 16] = pp;
        }
    }

    // ---- E6: argmax finalize + rare fp64 refine ----
    if (tid < 128) {
        const int row = tid;
        float M1 = pm1[0][row]; int I1 = pi1[0][row];
        float M2 = pm2[0][row]; int I2 = pi2[0][row];
        merge2(M1, I1, M2, I2, pm1[1][row], pi1[1][row], pm2[1][row], pi2[1][row]);
        int idx = I1;
        if (M1 - M2 < THR_) {
            const int b = row & 15, li = row >> 4;
            const size_t lg2 = lbase + li;
            const float* ar = hidden + ((size_t)b * L_ + lg2) * D1_;
            const int o1 = g * V_ + I1, o2 = g * V_ + I2;
            double s1 = (double)bias[o1], s2 = (double)bias[o2];
            const float* w1 = W + (size_t)o1 * D1_;
            const float* w2 = W + (size_t)o2 * D1_;
#pragma unroll 4
            for (int k = 0; k < D1_; ++k) {
                double a = (double)ar[k];
                s1 = fma(a, (double)w1[k], s1);
                s2 = fma(a, (double)w2[k], s2);
            }
            const size_t gb = (((size_t)b * L_ + lg2) * G_ + g) * V_;
            s1 += (double)gn[gb + I1]; s2 += (double)gn[gb + I2];
            if (s2 > s1 || (s2 == s1 && I2 < I1)) idx = I2;
        }
        IDX[row] = idx;
    }
    __syncthreads();

    // ---- E7: code-vector gather ----
#pragma unroll 1
    for (int it = 0; it < 24; ++it) {
        int i = tid + it * 512;                 // 0..12287 float4-tasks
        int row = i / 96, f = i - row * 96;
        int v = IDX[row];
        int b = row & 15, li = row >> 4;
        float4 val = *(const float4*)(cb + ((size_t)(g * V_ + v) * DG_) + f * 4);
        *(float4*)(out + ((size_t)b * L_ + lbase + li) * (G_ * DG_) + g * DG_ + f * 4) = val;
    }
}

extern "C" void kernel_launch(void* const* d_in, const int* in_sizes, int n_in,
                              void* d_out, int out_size, void* d_ws, size_t ws_size,
                              hipStream_t stream) {
    const float* hidden   = (const float*)d_in[0];
    const float* W        = (const float*)d_in[1];
    const float* bias     = (const float*)d_in[2];
    const float* codebook = (const float*)d_in[3];
    const float* gumbel   = (const float*)d_in[4];
    float* out = (float*)d_out;

    if (ws_size >= WS_BYTES_) {
        prep_w_kernel<<<320, 256, 0, stream>>>(W, (unsigned short*)d_ws);
        gvq3_kernel<true><<<512, 512, 0, stream>>>(hidden, W, bias, codebook, gumbel, out,
                                                   (const unsigned short*)d_ws);
    } else {
        gvq3_kernel<false><<<512, 512, 0, stream>>>(hidden, W, bias, codebook, gumbel, out,
                                                    (const unsigned short*)d_ws);
    }
}